// Round 5
// baseline (447.404 us; speedup 1.0000x reference)
//
#include <hip/hip_runtime.h>
#include <cstdint>
#include <cstddef>

#define HH 300
#define WW 400
#define HWPIX (HH*WW)

typedef __attribute__((ext_vector_type(8))) short short8_t;
typedef __attribute__((ext_vector_type(4))) float f32x4;

static __device__ __forceinline__ unsigned short f2bf(float f){
  union { float f; unsigned u; } v; v.f = f;
  unsigned r = (v.u + 0x7fffu + ((v.u >> 16) & 1u)) >> 16;
  return (unsigned short)r;
}
static __device__ __forceinline__ float bf2f(unsigned short us){
  union { unsigned u; float f; } v; v.u = ((unsigned)us) << 16;
  return v.f;
}
// True per-op-rounded dots: pragma blocks FMA contraction at IR level.
// (__fmul_rn/__fadd_rn are plain *,+ in ROCm and DO get contracted — this
// pragma was the R3 fix that made pixel binning bit-match numpy. KEEP.)
static __device__ __forceinline__ float dot4_x(float a0,float x0,float a1,float x1,
                                               float a2,float x2,float a3,float x3){
  #pragma clang fp contract(off)
  float s = a0*x0;
  s = s + a1*x1;
  s = s + a2*x2;
  s = s + a3*x3;
  return s;
}
static __device__ __forceinline__ float dot3_x(float a0,float x0,float a1,float x1,
                                               float a2,float x2){
  #pragma clang fp contract(off)
  float s = a0*x0;
  s = s + a1*x1;
  s = s + a2*x2;
  return s;
}

// ---------------------------------------------------------------------------
// prep: blocks 0..255 transpose+convert W1[0:256] -> W1aT (bf16, [n][k]);
// block 256 packs ntab[n][8] = {W1 rows 256..258 (vdir), W2 cols 0..2, b1, 0}
// and inverts poses.
// ---------------------------------------------------------------------------
__global__ void prep_kernel(const float* __restrict__ W1, const float* __restrict__ W2,
                            const float* __restrict__ b1, const float* __restrict__ pose,
                            float* __restrict__ poseinv, unsigned short* __restrict__ W1aT,
                            float* __restrict__ ntab, int B){
  int tid = threadIdx.x;
  int bid = blockIdx.x;
  if (bid < 256){
    int k = bid, n = tid;
    W1aT[n*256 + k] = f2bf(W1[k*256 + n]);
  } else {
    int n = tid;
    ntab[n*8+0] = W1[256*256 + n];
    ntab[n*8+1] = W1[257*256 + n];
    ntab[n*8+2] = W1[258*256 + n];
    ntab[n*8+3] = W2[n*3+0];
    ntab[n*8+4] = W2[n*3+1];
    ntab[n*8+5] = W2[n*3+2];
    ntab[n*8+6] = b1[n];
    ntab[n*8+7] = 0.f;
    if (tid < B){
      float M[4][8];
      const float* A = pose + tid*16;
      for (int i=0;i<4;i++) for (int j=0;j<4;j++){ M[i][j]=A[i*4+j]; M[i][4+j] = (i==j)?1.f:0.f; }
      for (int c=0;c<4;c++){
        int p=c;
        for (int r=c+1;r<4;r++) if (fabsf(M[r][c])>fabsf(M[p][c])) p=r;
        if (p!=c) for (int j=0;j<8;j++){ float t=M[c][j]; M[c][j]=M[p][j]; M[p][j]=t; }
        float inv = 1.f/M[c][c];
        for (int j=0;j<8;j++) M[c][j]*=inv;
        for (int r=0;r<4;r++) if (r!=c){ float f=M[r][c]; for(int j=0;j<8;j++) M[r][j]-=f*M[c][j]; }
      }
      float* O = poseinv + tid*16;
      for (int i=0;i<4;i++) for (int j=0;j<4;j++) O[i*4+j]=M[i][4+j];
    }
  }
}

// ---------------------------------------------------------------------------
// Kernel A: pure GEMM. H_base = feat @ W1a  (64 verts x 256 hid per block,
// K=256, bf16 MFMA — phase-1 structure proven in R3). New epilogue: pack acc
// into LDS [n][m] (stride 72 to dodge banks), then store the block's tile
// CONTIGUOUSLY to HT: tile b = HT + b*16384 elems, layout [n(256)][v_local(64)]
// bf16 — both the store here and the read in kernel B are fully coalesced.
// No phase-2 tail, no wave0 serialization.
// ---------------------------------------------------------------------------
__global__ __launch_bounds__(256) void gemm_kernel(
    const float* __restrict__ feat, const unsigned short* __restrict__ W1aT,
    unsigned short* __restrict__ HT, int N)
{
  __shared__ __align__(16) char smem[40960];
  unsigned short* sA  = (unsigned short*)smem;            // 64*64*2  = 8192 B
  unsigned short* sB  = (unsigned short*)(smem + 8192);   // 256*64*2 = 32768 B
  unsigned short* sHT = (unsigned short*)smem;            // epilogue: 256*72*2 = 36864 B

  const int tid  = threadIdx.x;
  const int lane = tid & 63;
  const int wv   = __builtin_amdgcn_readfirstlane(tid >> 6);
  const int lr   = lane & 15;
  const int qd   = lane >> 4;
  const int m0   = blockIdx.x * 64;

  f32x4 acc[4][4];
  for (int i=0;i<4;i++) for (int j=0;j<4;j++) acc[i][j] = (f32x4){0.f,0.f,0.f,0.f};

  for (int kt=0; kt<4; kt++){
    #pragma unroll
    for (int i=0;i<4;i++){
      int q   = i*256 + tid;
      int row = q >> 4;
      int c4  = q & 15;
      long rg = m0 + row; if (rg >= N) rg = N-1;
      float4 f = *(const float4*)(feat + rg*256 + kt*64 + c4*4);
      ushort4 u;
      u.x = f2bf(f.x); u.y = f2bf(f.y); u.z = f2bf(f.z); u.w = f2bf(f.w);
      int q8 = c4 >> 1, half = c4 & 1;
      int phys = q8 ^ (row & 7);
      *(ushort4*)(sA + row*64 + phys*8 + half*4) = u;
    }
    #pragma unroll
    for (int i=0;i<8;i++){
      int q  = i*256 + tid;
      int n  = q >> 3;
      int c8 = q & 7;
      uint4 v = *(const uint4*)(W1aT + n*256 + kt*64 + c8*8);
      int phys = c8 ^ (n & 7);
      *(uint4*)(sB + n*64 + phys*8) = v;
    }
    __syncthreads();
    #pragma unroll
    for (int ks=0; ks<2; ks++){
      short8_t av[4], bv[4];
      int qlog = ks*4 + qd;
      #pragma unroll
      for (int mt=0; mt<4; mt++){
        int row  = mt*16 + lr;
        int phys = qlog ^ (row & 7);
        av[mt] = *(const short8_t*)(sA + row*64 + phys*8);
      }
      #pragma unroll
      for (int nt=0; nt<4; nt++){
        int n    = wv*64 + nt*16 + lr;
        int phys = qlog ^ (n & 7);
        bv[nt] = *(const short8_t*)(sB + n*64 + phys*8);
      }
      #pragma unroll
      for (int mt=0; mt<4; mt++)
        #pragma unroll
        for (int nt=0; nt<4; nt++)
          acc[mt][nt] = __builtin_amdgcn_mfma_f32_16x16x32_bf16(av[mt], bv[nt], acc[mt][nt], 0,0,0);
    }
    __syncthreads();
  }

  // epilogue: acc -> sHT[n][m] (C/D: m = mt*16+qd*4+rr, n = wv*64+nt*16+lr),
  // rr pairs give adjacent m -> pack 2 bf16 per u32 write.
  #pragma unroll
  for (int nt=0; nt<4; nt++){
    int n = wv*64 + nt*16 + lr;
    #pragma unroll
    for (int mt=0; mt<4; mt++){
      #pragma unroll
      for (int rp=0; rp<2; rp++){
        int m = mt*16 + qd*4 + rp*2;
        unsigned u = (unsigned)f2bf(acc[mt][nt][rp*2]) |
                     ((unsigned)f2bf(acc[mt][nt][rp*2+1]) << 16);
        *(unsigned*)(sHT + n*72 + m) = u;
      }
    }
  }
  __syncthreads();

  // coalesced tile store: 256 n x 64 m bf16 = 32 KB
  unsigned short* tile = HT + (size_t)blockIdx.x * 16384;
  #pragma unroll
  for (int i=0;i<8;i++){
    int idx = i*256 + tid;
    int n = idx >> 3;       // 8 uint4 chunks per 64-elem row
    int c = idx & 7;
    uint4 v = *(const uint4*)(sHT + n*72 + c*8);
    *(uint4*)(tile + n*64 + c*8) = v;
  }
}

// ---------------------------------------------------------------------------
// Kernel B: barrier-free streaming. One thread = one vertex. Reads its h_base
// row from the blocked HT layout (64 consecutive verts per tile -> every
// wave load of HT is one 128B coalesced line). Weight table via wave-uniform
// s_loads. Both batches merged in the n-loop. Projection = proven
// contract(off) path. Scatter via per-thread atomics.
// ---------------------------------------------------------------------------
__global__ __launch_bounds__(256) void vertex_kernel(
    const unsigned short* __restrict__ HT, const float* __restrict__ ntab,
    const float* __restrict__ b2,
    const float* __restrict__ vp, const float* __restrict__ opy,
    const float* __restrict__ pose, const float* __restrict__ intr,
    const float* __restrict__ poseinv,
    float* __restrict__ num, float* __restrict__ den, int N, int B)
{
  int v = blockIdx.x*256 + threadIdx.x;
  if (v >= N) return;
  const unsigned short* tile = HT + (size_t)(v >> 6) * 16384 + (v & 63);

  float px = vp[v], py = vp[(size_t)N+v], pz = vp[2*(size_t)N+v];

  // per-batch geometry (B=2 assumed by register layout; loop handles general B<=2 pairs)
  float vd0[3], vd1[3];
  float up0,vq0,zz0, up1,vq1,zz1;
  for (int b=0; b<B; b++){
    const float* P  = pose + b*16;
    const float* Kc = intr + b*9;
    const float* Pi = poseinv + b*16;
    float xt = dot4_x(P[0],px, P[1],py, P[2], pz, P[3], 1.f);
    float yt = dot4_x(P[4],px, P[5],py, P[6], pz, P[7], 1.f);
    float zt = dot4_x(P[8],px, P[9],py, P[10],pz, P[11],1.f);
    float uu = dot3_x(Kc[0],xt, Kc[1],yt, Kc[2],zt);
    float vv = dot3_x(Kc[3],xt, Kc[4],yt, Kc[5],zt);
    float zp = dot3_x(Kc[6],xt, Kc[7],yt, Kc[8],zt);
    bool em = fabsf(zp) < 0.01f;
    float zsafe = em ? 0.01f : zp;
    float up = em ? -1e6f : uu/zsafe;
    float vq = em ? -1e6f : vv/zsafe;
    float zz = em ? -1e6f : zsafe;
    float inrm = 1.f/sqrtf(xt*xt + yt*yt + zt*zt);
    float nx=xt*inrm, ny=yt*inrm, nz=zt*inrm;
    float wx = Pi[0]*nx + Pi[1]*ny + Pi[2]*nz;
    float wy = Pi[4]*nx + Pi[5]*ny + Pi[6]*nz;
    float wz = Pi[8]*nx + Pi[9]*ny + Pi[10]*nz;
    if (b==0){ vd0[0]=wx; vd0[1]=wy; vd0[2]=wz; up0=up; vq0=vq; zz0=zz; }
    else     { vd1[0]=wx; vd1[1]=wy; vd1[2]=wz; up1=up; vq1=vq; zz1=zz; }
  }

  float a00=0.f,a01=0.f,a02=0.f, a10=0.f,a11=0.f,a12=0.f;
  #pragma unroll 4
  for (int n=0; n<256; n++){
    const float* t = ntab + n*8;          // loop-uniform -> s_load_dwordx8
    float hb = bf2f(tile[n*64]) + t[6];
    float h0 = fmaxf(hb + vd0[0]*t[0] + vd0[1]*t[1] + vd0[2]*t[2], 0.f);
    a00 += h0*t[3]; a01 += h0*t[4]; a02 += h0*t[5];
    float h1 = fmaxf(hb + vd1[0]*t[0] + vd1[1]*t[1] + vd1[2]*t[2], 0.f);
    a10 += h1*t[3]; a11 += h1*t[4]; a12 += h1*t[5];
  }

  float opac = 1.f/(1.f+expf(-opy[v]));   // clip(sigmoid,0,1) is a no-op

  // batch 0
  {
    int ix = (int)rintf(up0), iy = (int)rintf(vq0);
    if (ix>=0 && ix<WW && iy>=0 && iy<HH && zz0>=1.0f){
      float r0 = 1.f/(1.f+expf(-(a00 + b2[0])));
      float r1 = 1.f/(1.f+expf(-(a01 + b2[1])));
      float r2 = 1.f/(1.f+expf(-(a02 + b2[2])));
      int idx = iy*WW + ix;
      atomicAdd(den + idx, opac);
      atomicAdd(num + (size_t)0*HWPIX + idx, opac*r0);
      atomicAdd(num + (size_t)1*HWPIX + idx, opac*r1);
      atomicAdd(num + (size_t)2*HWPIX + idx, opac*r2);
    }
  }
  // batch 1
  if (B > 1){
    int ix = (int)rintf(up1), iy = (int)rintf(vq1);
    if (ix>=0 && ix<WW && iy>=0 && iy<HH && zz1>=1.0f){
      float r0 = 1.f/(1.f+expf(-(a10 + b2[0])));
      float r1 = 1.f/(1.f+expf(-(a11 + b2[1])));
      float r2 = 1.f/(1.f+expf(-(a12 + b2[2])));
      int idx = iy*WW + ix;
      atomicAdd(den + (size_t)HWPIX + idx, opac);
      atomicAdd(num + (size_t)3*HWPIX + idx, opac*r0);
      atomicAdd(num + (size_t)4*HWPIX + idx, opac*r1);
      atomicAdd(num + (size_t)5*HWPIX + idx, opac*r2);
    }
  }
}

// ---------------------------------------------------------------------------
// In-place: d_out currently holds num (B,3,HW); convert to final image.
__global__ void compose_kernel(float* __restrict__ out, const float* __restrict__ den,
                               const float* __restrict__ bkg, int B){
  int i = blockIdx.x*256 + threadIdx.x;
  int total = B*HWPIX;
  if (i >= total) return;
  int b = i / HWPIX;
  int pix = i - b*HWPIX;
  float d = den[i];
  float alpha = 1.f - expf(-d);
  float om = 1.f - alpha;
  float dd = d + 1e-8f;
  float* ob = out + (size_t)b*3*HWPIX;
  float f0 = ob[0*HWPIX + pix] / dd;
  float f1 = ob[1*HWPIX + pix] / dd;
  float f2 = ob[2*HWPIX + pix] / dd;
  ob[0*HWPIX + pix] = f0*alpha + bkg[0]*om;
  ob[1*HWPIX + pix] = f1*alpha + bkg[1]*om;
  ob[2*HWPIX + pix] = f2*alpha + bkg[2]*om;
}

// ---------------------------------------------------------------------------
extern "C" void kernel_launch(void* const* d_in, const int* in_sizes, int n_in,
                              void* d_out, int out_size, void* d_ws, size_t ws_size,
                              hipStream_t stream){
  const float* vp   = (const float*)d_in[0];
  // d_in[1] = ref_images: unused by the reference computation
  const float* pose = (const float*)d_in[2];
  const float* intr = (const float*)d_in[3];
  const float* feat = (const float*)d_in[4];
  const float* opy  = (const float*)d_in[5];
  const float* W1   = (const float*)d_in[6];
  const float* b1   = (const float*)d_in[7];
  const float* W2   = (const float*)d_in[8];
  const float* b2   = (const float*)d_in[9];
  const float* bkg  = (const float*)d_in[10];
  float* out = (float*)d_out;
  int N = in_sizes[0]/3;
  int B = in_sizes[2]/16;
  int nblk = (N + 63)/64;

  char* ws = (char*)d_ws;
  float* poseinv        = (float*)ws;                            // 256 B
  unsigned short* W1aT  = (unsigned short*)(ws + 256);           // 131072 B
  float* ntab           = (float*)(ws + 256 + 131072);           // 8192 B
  unsigned short* HT    = (unsigned short*)(ws + 139520);        // nblk*16384*2 B
  float* den            = (float*)(ws + 139520 + (size_t)nblk*32768);  // B*HWPIX*4 B

  hipMemsetAsync(out, 0, (size_t)out_size*sizeof(float), stream);
  hipMemsetAsync(den, 0, (size_t)B*HWPIX*sizeof(float), stream);
  prep_kernel<<<257, 256, 0, stream>>>(W1, W2, b1, pose, poseinv, W1aT, ntab, B);
  gemm_kernel<<<nblk, 256, 0, stream>>>(feat, W1aT, HT, N);
  vertex_kernel<<<(N + 255)/256, 256, 0, stream>>>(HT, ntab, b2, vp, opy,
                                                   pose, intr, poseinv, out, den, N, B);
  compose_kernel<<<(B*HWPIX + 255)/256, 256, 0, stream>>>(out, den, bkg, B);
}